// Round 20
// baseline (316.697 us; speedup 1.0000x reference)
//
#include <hip/hip_runtime.h>
#include <hip/hip_bf16.h>
#include <cstdint>

// Problem: B=32, T1=T2=512, D=128, gamma=1.0
// out[b] = softDTW( 1 - cos_sim(x[b], y[b]) )
//
// R20: ONE kernel, one block per batch (512 thr, 8 waves):
//   phase 0: normcast (own batch) -> xnb/ynb (global ws)
//   phase 1: 16 bf16-MFMA 128x128 tiles -> skew (anti-diag layout, global ws)
//   phase 2: DP (R9/R14/R18 structure, measured-best ~91 us)
//
// ws layout:
//   skew : 32*1023*512 floats = 16,760,832
//   xnb  : 32*512*128 bf16 (1,048,576 uints)
//   ynb  : same

#define BT      32
#define TLEN    512
#define DF      128
#define NDIAG   1023
#define BIGV    1e30f
#define INV_LN2 1.44269504088896340f
#define LN2     0.69314718055994531f

typedef short bf16x8 __attribute__((ext_vector_type(8)));
typedef float f32x4  __attribute__((ext_vector_type(4)));

__device__ __forceinline__ unsigned f2bf(float f) {     // RNE f32 -> bf16 bits
    unsigned u = __builtin_bit_cast(unsigned, f);
    return (u + 0x7FFFu + ((u >> 16) & 1u)) >> 16;
}

__device__ __forceinline__ int clampi(int v) {
    return v < 0 ? 0 : (v > NDIAG - 1 ? NDIAG - 1 : v);
}

__device__ __forceinline__ float dpp_shr1_old(float old, float x) {
    return __builtin_bit_cast(float,
        __builtin_amdgcn_update_dpp(__builtin_bit_cast(int, old),
                                    __builtin_bit_cast(int, x),
                                    0x138 /*wave_shr:1*/, 0xF, 0xF, false));
}

#define LDSTRIDE 272                         // bytes per LDS row (136 bf16)

// ----- DP phase macros (R18 verbatim) -----
#define PH(s, CC, PN, PO, NQC, MASKED, CLAMPED)                                \
  {                                                                            \
    float up_ = dpp_shr1_old(bd_up, PN);                                       \
    float dg_ = dgs;                                                           \
    float m_   = fminf(fminf(dg_, PN), up_);                                   \
    float mid_ = __builtin_amdgcn_fmed3f(dg_, PN, up_);                        \
    float mx_  = fmaxf(fmaxf(dg_, PN), up_);                                   \
    float e_   = 1.0f + __builtin_amdgcn_exp2f(m_ - mid_)                      \
                      + __builtin_amdgcn_exp2f(m_ - mx_);                      \
    float v_   = CC + m_ - __builtin_amdgcn_logf(e_);                          \
    PO = (MASKED) ? (((unsigned)(vb0 + (s)) < 512u) ? v_ : vBig) : v_;         \
    if (((s) & 3) == 0) bq.x = PO;                                             \
    if (((s) & 3) == 1) bq.y = PO;                                             \
    if (((s) & 3) == 2) bq.z = PO;                                             \
    if (((s) & 3) == 3) { bq.w = PO;                                           \
      if (lt == 63) bnd4[c + 1][(q0 + ((s) >> 2)) & 7] = bq; }                 \
    bd_up = (NQC);                                                             \
    dgs = up_;                                                                 \
    { int kl_ = kd0 + (s) + 8; if (CLAMPED) kl_ = clampi(kl_);                 \
      CC = skb[(size_t)kl_ * TLEN]; }                                          \
  }

#define SEG_BODY(MASKED, CLAMPED)                                              \
    PH(0,  c0, P, Q, nq0.x, MASKED, CLAMPED) PH(1,  c1, Q, P, nq0.y, MASKED, CLAMPED) \
    PH(2,  c2, P, Q, nq0.z, MASKED, CLAMPED) PH(3,  c3, Q, P, nq0.w, MASKED, CLAMPED) \
    PH(4,  c4, P, Q, nq1.x, MASKED, CLAMPED) PH(5,  c5, Q, P, nq1.y, MASKED, CLAMPED) \
    PH(6,  c6, P, Q, nq1.z, MASKED, CLAMPED) PH(7,  c7, Q, P, nq1.w, MASKED, CLAMPED) \
    PH(8,  c0, P, Q, nq2.x, MASKED, CLAMPED) PH(9,  c1, Q, P, nq2.y, MASKED, CLAMPED) \
    PH(10, c2, P, Q, nq2.z, MASKED, CLAMPED) PH(11, c3, Q, P, nq2.w, MASKED, CLAMPED) \
    PH(12, c4, P, Q, nq3.x, MASKED, CLAMPED) PH(13, c5, Q, P, nq3.y, MASKED, CLAMPED) \
    PH(14, c6, P, Q, nq3.z, MASKED, CLAMPED) PH(15, c7, Q, P, nq3.w, MASKED, CLAMPED)

#define PRIME(K)                                                               \
    c0 = skb[(size_t)clampi((K) + 0) * TLEN];                                  \
    c1 = skb[(size_t)clampi((K) + 1) * TLEN];                                  \
    c2 = skb[(size_t)clampi((K) + 2) * TLEN];                                  \
    c3 = skb[(size_t)clampi((K) + 3) * TLEN];                                  \
    c4 = skb[(size_t)clampi((K) + 4) * TLEN];                                  \
    c5 = skb[(size_t)clampi((K) + 5) * TLEN];                                  \
    c6 = skb[(size_t)clampi((K) + 6) * TLEN];                                  \
    c7 = skb[(size_t)clampi((K) + 7) * TLEN];

__global__ __launch_bounds__(512) void sdtw_fused(const float* __restrict__ x,
                                                  const float* __restrict__ y,
                                                  unsigned* __restrict__ xnb,
                                                  unsigned* __restrict__ ynb,
                                                  float* __restrict__ skew,
                                                  float* __restrict__ out) {
    __shared__ __align__(16) char smem[69632];   // GEMM: A(34816)+B(34816); epi: cs[128][130]
    __shared__ float4 bnd4[9][8];                // DP boundary quads

    const int b   = blockIdx.x;
    const int tid = threadIdx.x;
    const int ww  = tid >> 6;
    const int l   = tid & 63;

    // ---------------- phase 0: normalize + cast own batch ----------------
    {
        const float* xb = x + (size_t)b * TLEN * DF;
        const float* yb = y + (size_t)b * TLEN * DF;
        unsigned* xo = xnb + (size_t)b * TLEN * 64;
        unsigned* yo = ynb + (size_t)b * TLEN * 64;
        for (int i = 0; i < 128; ++i) {
            int g = ww * 128 + i;                // 0..1023
            const float* src = (g < 512) ? xb + (size_t)g * DF
                                         : yb + (size_t)(g - 512) * DF;
            unsigned* dst = (g < 512) ? xo + (size_t)g * 64
                                      : yo + (size_t)(g - 512) * 64;
            float2 v = reinterpret_cast<const float2*>(src)[l];
            float s = v.x * v.x + v.y * v.y;
            #pragma unroll
            for (int o = 32; o; o >>= 1) s += __shfl_xor(s, o);
            float scale = 1.0f / fmaxf(sqrtf(s), 1e-12f);
            dst[l] = f2bf(v.x * scale) | (f2bf(v.y * scale) << 16);
        }
    }
    __threadfence();
    __syncthreads();

    // ---------------- phase 1: 16 MFMA tiles -> skew ----------------
    {
        char* As = smem;
        char* Bs = smem + 34816;
        const int lr = l & 15, lg = l >> 4;
        float* sk = skew + (size_t)b * (NDIAG * TLEN);

        for (int tr = 0; tr < 4; ++tr) {
            for (int tc = 0; tc < 4; ++tc) {
                const int r0 = tr * 128, c0 = tc * 128;
                const char* xg = (const char*)(xnb + ((size_t)b * TLEN + r0) * 64);
                const char* yg = (const char*)(ynb + ((size_t)b * TLEN + c0) * 64);

                #pragma unroll
                for (int p = 0; p < 4; ++p) {    // stage A,B (512 thr, 4 passes)
                    int idx = p * 512 + tid;
                    int row = idx >> 4, u = idx & 15;
                    *(uint4*)(As + row * LDSTRIDE + u * 16) = *(const uint4*)(xg + row * 256 + u * 16);
                    *(uint4*)(Bs + row * LDSTRIDE + u * 16) = *(const uint4*)(yg + row * 256 + u * 16);
                }
                __syncthreads();

                f32x4 acc[8];
                #pragma unroll
                for (int rt = 0; rt < 8; ++rt) acc[rt] = (f32x4){0.f, 0.f, 0.f, 0.f};

                #pragma unroll
                for (int kb = 0; kb < 4; ++kb) {
                    bf16x8 af[8], bfr;
                    #pragma unroll
                    for (int rt = 0; rt < 8; ++rt)
                        af[rt] = *(const bf16x8*)(As + (rt * 16 + lr) * LDSTRIDE + kb * 64 + lg * 16);
                    bfr = *(const bf16x8*)(Bs + (ww * 16 + lr) * LDSTRIDE + kb * 64 + lg * 16);
                    #pragma unroll
                    for (int rt = 0; rt < 8; ++rt)
                        acc[rt] = __builtin_amdgcn_mfma_f32_16x16x32_bf16(af[rt], bfr, acc[rt], 0, 0, 0);
                }

                __syncthreads();                 // frag reads done; reuse LDS as cs
                float* cs = (float*)smem;        // [128][130]
                #pragma unroll
                for (int rt = 0; rt < 8; ++rt)
                    #pragma unroll
                    for (int r = 0; r < 4; ++r) {
                        int row = rt * 16 + lg * 4 + r;  // C/D: row=(l>>4)*4+reg
                        int col = ww * 16 + lr;          //      col=l&15
                        cs[row * 130 + col] = (1.0f - acc[rt][r]) * INV_LN2;
                    }
                __syncthreads();

                for (int dd = ww; dd < 255; dd += 8) {
                    int lo = max(0, dd - 127), hi = min(127, dd);
                    for (int rb = lo; rb <= hi; rb += 64) {
                        int rl = rb + l;
                        if (rl <= hi)
                            sk[(size_t)(r0 + c0 + dd) * TLEN + r0 + rl] = cs[rl * 129 + dd];
                    }
                }
                __syncthreads();                 // cs consumed; safe to restage
            }
        }
    }
    __threadfence();

    // ---------------- phase 2: DP (R18 structure) ----------------
    const int c   = ((ww & 3) << 1) | (ww >> 2); // chunk (SIMD-aware remap)
    const int lt  = l;
    const int row = 64 * c + lt;
    const float* skb = skew + (size_t)b * (NDIAG * TLEN) + row;

    if (tid < 288) ((float*)bnd4)[tid] = BIGV;

    float P = BIGV, Q = BIGV;
    float vBig  = BIGV;
    float bd_up = BIGV;
    float dgs   = (tid == 0) ? 0.0f : BIGV;      // R(0,0)=0 at kd=0 (chunk0 lane0)
    float4 bq = make_float4(BIGV, BIGV, BIGV, BIGV);

    __syncthreads();

    float c0, c1, c2, c3, c4, c5, c6, c7;
    PRIME(-16 * c)

    for (int s = 0; s < 71; ++s) {
        const int sw  = s - 5 * c;
        const int kd0 = 16 * (s - c);
        const int q0  = (kd0 >> 2) & 7;
        const int vb0 = kd0 - row;

        if (sw >= -1 && sw <= 35) {
            float4 nq0 = bnd4[c][q0];
            float4 nq1 = bnd4[c][(q0 + 1) & 7];
            float4 nq2 = bnd4[c][(q0 + 2) & 7];
            float4 nq3 = bnd4[c][(q0 + 3) & 7];
            if (sw == -1) { PRIME(kd0) }
            if (sw >= 4 && sw <= 31) { SEG_BODY(0, 0) }
            else                     { SEG_BODY(1, 1) }
        } else {
            if (lt == 63) {
                float4 bigq = make_float4(BIGV, BIGV, BIGV, BIGV);
                bnd4[c + 1][q0]           = bigq;
                bnd4[c + 1][(q0 + 1) & 7] = bigq;
                bnd4[c + 1][(q0 + 2) & 7] = bigq;
                bnd4[c + 1][(q0 + 3) & 7] = bigq;
            }
        }
        __syncthreads();
    }

    if (tid == 511) out[b] = Q * LN2;            // chunk 7, row 511: R'(512,512)*ln2
}

// ---------------------------------------------------------------- launcher
extern "C" void kernel_launch(void* const* d_in, const int* in_sizes, int n_in,
                              void* d_out, int out_size, void* d_ws, size_t ws_size,
                              hipStream_t stream) {
    const float* x = (const float*)d_in[0];
    const float* y = (const float*)d_in[1];
    float* outp = (float*)d_out;

    float*    skew = (float*)d_ws;                        // 16,760,832 floats
    unsigned* xnb  = (unsigned*)(skew + (size_t)16760832);
    unsigned* ynb  = xnb + 1048576;

    sdtw_fused<<<dim3(BT), dim3(512), 0, stream>>>(x, y, xnb, ynb, skew, outp);
}

// Round 21
// 154.979 us; speedup vs baseline: 2.0435x; 2.0435x over previous
//
#include <hip/hip_runtime.h>
#include <hip/hip_bf16.h>
#include <cstdint>

// Problem: B=32, T1=T2=512, D=128, gamma=1.0
// out[b] = softDTW( 1 - cos_sim(x[b], y[b]) )
//
// R21: normcast kernel, then ONE mega-launch (544 blocks x 512 thr):
//   blocks 0..31   : DP (R18 structure), gated per segment on band flags
//   blocks 32..543 : one 128x128 bf16-MFMA tile each -> skew, then release-add
//                    flags[b][tr+tc]
// Device-scope acquire/release atomics carry cross-XCD visibility (G16).
//
// ws layout:
//   skew  : 32*1023*512 floats = 16,760,832
//   xnb   : 32*512*128 bf16 (1,048,576 uints)
//   ynb   : same
//   flags : 32*7 ints (zeroed each call via hipMemsetAsync)

#define BT      32
#define TLEN    512
#define DF      128
#define NDIAG   1023
#define BIGV    1e30f
#define INV_LN2 1.44269504088896340f
#define LN2     0.69314718055994531f

typedef short bf16x8 __attribute__((ext_vector_type(8)));
typedef float f32x4  __attribute__((ext_vector_type(4)));

__device__ __forceinline__ unsigned f2bf(float f) {
    unsigned u = __builtin_bit_cast(unsigned, f);
    return (u + 0x7FFFu + ((u >> 16) & 1u)) >> 16;
}

__device__ __forceinline__ int clampi(int v) {
    return v < 0 ? 0 : (v > NDIAG - 1 ? NDIAG - 1 : v);
}

__device__ __forceinline__ float dpp_shr1_old(float old, float x) {
    return __builtin_bit_cast(float,
        __builtin_amdgcn_update_dpp(__builtin_bit_cast(int, old),
                                    __builtin_bit_cast(int, x),
                                    0x138 /*wave_shr:1*/, 0xF, 0xF, false));
}

#define LDSTRIDE 272                         // bytes per LDS row (136 bf16)

// ---------------------------------------------- normalize + cast to bf16
__global__ __launch_bounds__(256) void sdtw_normcast(const float* __restrict__ x,
                                                     const float* __restrict__ y,
                                                     unsigned* __restrict__ ox,
                                                     unsigned* __restrict__ oy) {
    const float* in  = blockIdx.y ? y : x;
    unsigned*    out = blockIdx.y ? oy : ox;
    int row = blockIdx.x * 4 + (threadIdx.x >> 6);
    int t   = threadIdx.x & 63;
    float2 v = reinterpret_cast<const float2*>(in + (size_t)row * DF)[t];
    float s = v.x * v.x + v.y * v.y;
    #pragma unroll
    for (int o = 32; o; o >>= 1) s += __shfl_xor(s, o);
    float scale = 1.0f / fmaxf(sqrtf(s), 1e-12f);
    out[(size_t)row * 64 + t] = f2bf(v.x * scale) | (f2bf(v.y * scale) << 16);
}

// ----- DP phase macros (R18 verbatim) -----
#define PH(s, CC, PN, PO, NQC, MASKED, CLAMPED)                                \
  {                                                                            \
    float up_ = dpp_shr1_old(bd_up, PN);                                       \
    float dg_ = dgs;                                                           \
    float m_   = fminf(fminf(dg_, PN), up_);                                   \
    float mid_ = __builtin_amdgcn_fmed3f(dg_, PN, up_);                        \
    float mx_  = fmaxf(fmaxf(dg_, PN), up_);                                   \
    float e_   = 1.0f + __builtin_amdgcn_exp2f(m_ - mid_)                      \
                      + __builtin_amdgcn_exp2f(m_ - mx_);                      \
    float v_   = CC + m_ - __builtin_amdgcn_logf(e_);                          \
    PO = (MASKED) ? (((unsigned)(vb0 + (s)) < 512u) ? v_ : vBig) : v_;         \
    if (((s) & 3) == 0) bq.x = PO;                                             \
    if (((s) & 3) == 1) bq.y = PO;                                             \
    if (((s) & 3) == 2) bq.z = PO;                                             \
    if (((s) & 3) == 3) { bq.w = PO;                                           \
      if (lt == 63) bnd4[c + 1][(q0 + ((s) >> 2)) & 7] = bq; }                 \
    bd_up = (NQC);                                                             \
    dgs = up_;                                                                 \
    { int kl_ = kd0 + (s) + 8; if (CLAMPED) kl_ = clampi(kl_);                 \
      CC = skb[(size_t)kl_ * TLEN]; }                                          \
  }

#define SEG_BODY(MASKED, CLAMPED)                                              \
    PH(0,  c0, P, Q, nq0.x, MASKED, CLAMPED) PH(1,  c1, Q, P, nq0.y, MASKED, CLAMPED) \
    PH(2,  c2, P, Q, nq0.z, MASKED, CLAMPED) PH(3,  c3, Q, P, nq0.w, MASKED, CLAMPED) \
    PH(4,  c4, P, Q, nq1.x, MASKED, CLAMPED) PH(5,  c5, Q, P, nq1.y, MASKED, CLAMPED) \
    PH(6,  c6, P, Q, nq1.z, MASKED, CLAMPED) PH(7,  c7, Q, P, nq1.w, MASKED, CLAMPED) \
    PH(8,  c0, P, Q, nq2.x, MASKED, CLAMPED) PH(9,  c1, Q, P, nq2.y, MASKED, CLAMPED) \
    PH(10, c2, P, Q, nq2.z, MASKED, CLAMPED) PH(11, c3, Q, P, nq2.w, MASKED, CLAMPED) \
    PH(12, c4, P, Q, nq3.x, MASKED, CLAMPED) PH(13, c5, Q, P, nq3.y, MASKED, CLAMPED) \
    PH(14, c6, P, Q, nq3.z, MASKED, CLAMPED) PH(15, c7, Q, P, nq3.w, MASKED, CLAMPED)

#define PRIME(K)                                                               \
    c0 = skb[(size_t)clampi((K) + 0) * TLEN];                                  \
    c1 = skb[(size_t)clampi((K) + 1) * TLEN];                                  \
    c2 = skb[(size_t)clampi((K) + 2) * TLEN];                                  \
    c3 = skb[(size_t)clampi((K) + 3) * TLEN];                                  \
    c4 = skb[(size_t)clampi((K) + 4) * TLEN];                                  \
    c5 = skb[(size_t)clampi((K) + 5) * TLEN];                                  \
    c6 = skb[(size_t)clampi((K) + 6) * TLEN];                                  \
    c7 = skb[(size_t)clampi((K) + 7) * TLEN];

__global__ __launch_bounds__(512) void sdtw_mega(const unsigned* __restrict__ xnb,
                                                 const unsigned* __restrict__ ynb,
                                                 float* __restrict__ skew,
                                                 int* __restrict__ flags,
                                                 float* __restrict__ out) {
    __shared__ __align__(16) char smem[69632];
    __shared__ int s_ready;
    const int tid = threadIdx.x;

    if (blockIdx.x >= 32) {
        // ================= GEMM tile producer =================
        const int idx = blockIdx.x - 32;
        const int b = idx >> 4, tr = (idx >> 2) & 3, tc = idx & 3;
        const int r0 = tr * 128, c0 = tc * 128;
        const int ww = tid >> 6, l = tid & 63;
        const int lr = l & 15, lg = l >> 4;
        char* As = smem;
        char* Bs = smem + 34816;

        const char* xg = (const char*)(xnb + ((size_t)b * TLEN + r0) * 64);
        const char* yg = (const char*)(ynb + ((size_t)b * TLEN + c0) * 64);

        #pragma unroll
        for (int p = 0; p < 4; ++p) {
            int i2 = p * 512 + tid;
            int row = i2 >> 4, u = i2 & 15;
            *(uint4*)(As + row * LDSTRIDE + u * 16) = *(const uint4*)(xg + row * 256 + u * 16);
            *(uint4*)(Bs + row * LDSTRIDE + u * 16) = *(const uint4*)(yg + row * 256 + u * 16);
        }
        __syncthreads();

        f32x4 acc[8];
        #pragma unroll
        for (int rt = 0; rt < 8; ++rt) acc[rt] = (f32x4){0.f, 0.f, 0.f, 0.f};

        #pragma unroll
        for (int kb = 0; kb < 4; ++kb) {
            bf16x8 af[8], bfr;
            #pragma unroll
            for (int rt = 0; rt < 8; ++rt)
                af[rt] = *(const bf16x8*)(As + (rt * 16 + lr) * LDSTRIDE + kb * 64 + lg * 16);
            bfr = *(const bf16x8*)(Bs + (ww * 16 + lr) * LDSTRIDE + kb * 64 + lg * 16);
            #pragma unroll
            for (int rt = 0; rt < 8; ++rt)
                acc[rt] = __builtin_amdgcn_mfma_f32_16x16x32_bf16(af[rt], bfr, acc[rt], 0, 0, 0);
        }

        __syncthreads();
        float* cs = (float*)smem;            // [128][130]
        #pragma unroll
        for (int rt = 0; rt < 8; ++rt)
            #pragma unroll
            for (int r = 0; r < 4; ++r) {
                int row = rt * 16 + lg * 4 + r;
                int col = ww * 16 + lr;
                cs[row * 130 + col] = (1.0f - acc[rt][r]) * INV_LN2;
            }
        __syncthreads();

        float* sk = skew + (size_t)b * (NDIAG * TLEN);
        for (int dd = ww; dd < 255; dd += 8) {
            int lo = max(0, dd - 127), hi = min(127, dd);
            for (int rb = lo; rb <= hi; rb += 64) {
                int rl = rb + l;
                if (rl <= hi)
                    sk[(size_t)(r0 + c0 + dd) * TLEN + r0 + rl] = cs[rl * 129 + dd];
            }
        }
        __syncthreads();                     // all waves' stores drained (vmcnt0)
        if (tid == 0)
            __hip_atomic_fetch_add(&flags[b * 7 + tr + tc], 1,
                                   __ATOMIC_RELEASE, __HIP_MEMORY_SCOPE_AGENT);
        return;
    }

    // ================= DP consumer (R18 structure) =================
    const int b   = blockIdx.x;
    const int ww  = tid >> 6;
    const int c   = ((ww & 3) << 1) | (ww >> 2);
    const int lt  = tid & 63;
    const int row = 64 * c + lt;
    const float* skb = skew + (size_t)b * (NDIAG * TLEN) + row;
    const int b7 = b * 7;

    float4 (*bnd4)[8] = (float4(*)[8])smem;      // [9][8] quads
    if (tid < 288) ((float*)bnd4)[tid] = BIGV;
    if (tid == 0) s_ready = -1;

    float P = BIGV, Q = BIGV;
    float vBig  = BIGV;
    float bd_up = BIGV;
    float dgs   = (tid == 0) ? 0.0f : BIGV;
    float4 bq = make_float4(BIGV, BIGV, BIGV, BIGV);

    __syncthreads();

    // pre-gate: band 0 must be complete before the initial PRIME (diags 0..7)
    if (tid == 0) {
        while (__hip_atomic_load(&flags[b7 + 0], __ATOMIC_ACQUIRE,
                                 __HIP_MEMORY_SCOPE_AGENT) < 1)
            __builtin_amdgcn_s_sleep(8);
        s_ready = 0;
    }
    __syncthreads();

    float c0, c1, c2, c3, c4, c5, c6, c7;
    PRIME(-16 * c)

    for (int s = 0; s < 71; ++s) {
        if (s_ready < 6) {                       // uniform (read after barrier)
            if (tid == 0) {
                int nb = (16 * s + 23) >> 7; if (nb > 6) nb = 6;
                int r = s_ready;
                while (r < 6) {
                    int d = r + 1;
                    int need = 4 - (d > 3 ? d - 3 : 3 - d);
                    if (__hip_atomic_load(&flags[b7 + d], __ATOMIC_ACQUIRE,
                                          __HIP_MEMORY_SCOPE_AGENT) >= need) r = d;
                    else if (r >= nb) break;     // opportunistic advance only
                    else __builtin_amdgcn_s_sleep(8);
                }
                s_ready = r;
            }
            __syncthreads();
        }

        const int sw  = s - 5 * c;
        const int kd0 = 16 * (s - c);
        const int q0  = (kd0 >> 2) & 7;
        const int vb0 = kd0 - row;

        if (sw >= -1 && sw <= 35) {
            float4 nq0 = bnd4[c][q0];
            float4 nq1 = bnd4[c][(q0 + 1) & 7];
            float4 nq2 = bnd4[c][(q0 + 2) & 7];
            float4 nq3 = bnd4[c][(q0 + 3) & 7];
            if (sw == -1) { PRIME(kd0) }
            if (sw >= 4 && sw <= 31) { SEG_BODY(0, 0) }
            else                     { SEG_BODY(1, 1) }
        } else {
            if (lt == 63) {
                float4 bigq = make_float4(BIGV, BIGV, BIGV, BIGV);
                bnd4[c + 1][q0]           = bigq;
                bnd4[c + 1][(q0 + 1) & 7] = bigq;
                bnd4[c + 1][(q0 + 2) & 7] = bigq;
                bnd4[c + 1][(q0 + 3) & 7] = bigq;
            }
        }
        __syncthreads();
    }

    if (tid == 511) out[b] = Q * LN2;            // chunk 7, row 511
}

// ---------------------------------------------------------------- launcher
extern "C" void kernel_launch(void* const* d_in, const int* in_sizes, int n_in,
                              void* d_out, int out_size, void* d_ws, size_t ws_size,
                              hipStream_t stream) {
    const float* x = (const float*)d_in[0];
    const float* y = (const float*)d_in[1];
    float* outp = (float*)d_out;

    float*    skew  = (float*)d_ws;                       // 16,760,832 floats
    unsigned* xnb   = (unsigned*)(skew + (size_t)16760832);
    unsigned* ynb   = xnb + 1048576;
    int*      flags = (int*)(ynb + 1048576);              // 32*7 ints

    hipMemsetAsync(flags, 0, BT * 7 * sizeof(int), stream);
    sdtw_normcast<<<dim3(BT * TLEN / 4, 2), dim3(256), 0, stream>>>(x, y, xnb, ynb);
    sdtw_mega<<<dim3(544), dim3(512), 0, stream>>>(xnb, ynb, skew, flags, outp);
}

// Round 22
// 128.146 us; speedup vs baseline: 2.4714x; 1.2094x over previous
//
#include <hip/hip_runtime.h>
#include <hip/hip_bf16.h>
#include <cstdint>

// Problem: B=32, T1=T2=512, D=128, gamma=1.0
// out[b] = softDTW( 1 - cos_sim(x[b], y[b]) )
//
// R22 = R18 (best measured: 122.6 us) with skew stored as FP16:
// GEMM was write-BW-bound (~67 MB @ ~3.5 TB/s); fp16 halves it. DP is
// latency-bound (2.7% HBM) -> unaffected by read width; converts on load.
// Precision: skew in [0,2.89], fp16 ulp<=0.002, path random-walk ~0.02 << 1.51.
//
// ws layout:
//   skew : 32*1023*512 halves (33.5 MB)
//   xnb  : 32*512*128 bf16 (1,048,576 uints)
//   ynb  : same

#define BT      32
#define TLEN    512
#define DF      128
#define NDIAG   1023
#define BIGV    1e30f
#define INV_LN2 1.44269504088896340f
#define LN2     0.69314718055994531f

typedef short bf16x8 __attribute__((ext_vector_type(8)));
typedef float f32x4  __attribute__((ext_vector_type(4)));
typedef _Float16 half_t;

__device__ __forceinline__ unsigned f2bf(float f) {     // RNE f32 -> bf16 bits
    unsigned u = __builtin_bit_cast(unsigned, f);
    return (u + 0x7FFFu + ((u >> 16) & 1u)) >> 16;
}

// ---------------------------------------------- normalize + cast to bf16
__global__ __launch_bounds__(256) void sdtw_normcast(const float* __restrict__ x,
                                                     const float* __restrict__ y,
                                                     unsigned* __restrict__ ox,
                                                     unsigned* __restrict__ oy) {
    const float* in  = blockIdx.y ? y : x;
    unsigned*    out = blockIdx.y ? oy : ox;
    int row = blockIdx.x * 4 + (threadIdx.x >> 6);
    int t   = threadIdx.x & 63;
    float2 v = reinterpret_cast<const float2*>(in + (size_t)row * DF)[t];
    float s = v.x * v.x + v.y * v.y;
    #pragma unroll
    for (int o = 32; o; o >>= 1) s += __shfl_xor(s, o);
    float scale = 1.0f / fmaxf(sqrtf(s), 1e-12f);
    out[(size_t)row * 64 + t] = f2bf(v.x * scale) | (f2bf(v.y * scale) << 16);
}

// ---------------------------------------------- bf16 MFMA GEMM -> skew (fp16)
#define LDSTRIDE 272                         // bytes per LDS row (136 bf16)

__global__ __launch_bounds__(256) void sdtw_gemm_skew(const unsigned* __restrict__ xnb,
                                                      const unsigned* __restrict__ ynb,
                                                      half_t* __restrict__ skew) {
    __shared__ short smem[34816];            // 69,632 B: A + B
    char* As = (char*)smem;
    char* Bs = (char*)smem + 34816;

    const int b  = blockIdx.z;
    const int r0 = blockIdx.y * 128;
    const int c0 = blockIdx.x * 128;
    const int tid = threadIdx.x;
    const int wid = tid >> 6, l = tid & 63;
    const int lr = l & 15, lg = l >> 4;

    const char* xg = (const char*)(xnb + ((size_t)b * TLEN + r0) * 64);
    const char* yg = (const char*)(ynb + ((size_t)b * TLEN + c0) * 64);

    #pragma unroll
    for (int p = 0; p < 8; ++p) {
        int idx = p * 256 + tid;
        int row = idx >> 4, u = idx & 15;
        *(uint4*)(As + row * LDSTRIDE + u * 16) = *(const uint4*)(xg + row * 256 + u * 16);
        *(uint4*)(Bs + row * LDSTRIDE + u * 16) = *(const uint4*)(yg + row * 256 + u * 16);
    }
    __syncthreads();

    f32x4 acc[8][2];
    #pragma unroll
    for (int rt = 0; rt < 8; ++rt)
        #pragma unroll
        for (int ct = 0; ct < 2; ++ct) acc[rt][ct] = (f32x4){0.f, 0.f, 0.f, 0.f};

    #pragma unroll
    for (int kb = 0; kb < 4; ++kb) {
        bf16x8 af[8], bfr[2];
        #pragma unroll
        for (int rt = 0; rt < 8; ++rt)
            af[rt] = *(const bf16x8*)(As + (rt * 16 + lr) * LDSTRIDE + kb * 64 + lg * 16);
        #pragma unroll
        for (int ct = 0; ct < 2; ++ct)
            bfr[ct] = *(const bf16x8*)(Bs + (wid * 32 + ct * 16 + lr) * LDSTRIDE + kb * 64 + lg * 16);
        #pragma unroll
        for (int rt = 0; rt < 8; ++rt)
            #pragma unroll
            for (int ct = 0; ct < 2; ++ct)
                acc[rt][ct] = __builtin_amdgcn_mfma_f32_16x16x32_bf16(af[rt], bfr[ct], acc[rt][ct], 0, 0, 0);
    }

    __syncthreads();
    float* cs = (float*)smem;                // [128][130]
    #pragma unroll
    for (int rt = 0; rt < 8; ++rt)
        #pragma unroll
        for (int ct = 0; ct < 2; ++ct)
            #pragma unroll
            for (int r = 0; r < 4; ++r) {
                int row = rt * 16 + lg * 4 + r;
                int col = wid * 32 + ct * 16 + lr;
                cs[row * 130 + col] = (1.0f - acc[rt][ct][r]) * INV_LN2;
            }
    __syncthreads();

    half_t* sk = skew + (size_t)b * (NDIAG * TLEN);
    for (int dd = wid; dd < 255; dd += 4) {
        int lo = max(0, dd - 127), hi = min(127, dd);
        for (int rb = lo; rb <= hi; rb += 64) {
            int rl = rb + l;
            if (rl <= hi)
                sk[(size_t)(r0 + c0 + dd) * TLEN + r0 + rl] = (half_t)cs[rl * 129 + dd];
        }
    }
}

// ----------------------------------------------------------------- DTW DP
// (R9/R14/R18 structure, measured best ~91 us; loads fp16, converts to f32.)
__device__ __forceinline__ int clampi(int v) {
    return v < 0 ? 0 : (v > NDIAG - 1 ? NDIAG - 1 : v);
}

__device__ __forceinline__ float dpp_shr1_old(float old, float x) {
    return __builtin_bit_cast(float,
        __builtin_amdgcn_update_dpp(__builtin_bit_cast(int, old),
                                    __builtin_bit_cast(int, x),
                                    0x138 /*wave_shr:1*/, 0xF, 0xF, false));
}

#define PH(s, CC, PN, PO, NQC, MASKED, CLAMPED)                                \
  {                                                                            \
    float up_ = dpp_shr1_old(bd_up, PN);                                       \
    float dg_ = dgs;                                                           \
    float m_   = fminf(fminf(dg_, PN), up_);                                   \
    float mid_ = __builtin_amdgcn_fmed3f(dg_, PN, up_);                        \
    float mx_  = fmaxf(fmaxf(dg_, PN), up_);                                   \
    float e_   = 1.0f + __builtin_amdgcn_exp2f(m_ - mid_)                      \
                      + __builtin_amdgcn_exp2f(m_ - mx_);                      \
    float v_   = (float)CC + m_ - __builtin_amdgcn_logf(e_);                   \
    PO = (MASKED) ? (((unsigned)(vb0 + (s)) < 512u) ? v_ : vBig) : v_;         \
    if (((s) & 3) == 0) bq.x = PO;                                             \
    if (((s) & 3) == 1) bq.y = PO;                                             \
    if (((s) & 3) == 2) bq.z = PO;                                             \
    if (((s) & 3) == 3) { bq.w = PO;                                           \
      if (lt == 63) bnd4[c + 1][(q0 + ((s) >> 2)) & 7] = bq; }                 \
    bd_up = (NQC);                                                             \
    dgs = up_;                                                                 \
    { int kl_ = kd0 + (s) + 8; if (CLAMPED) kl_ = clampi(kl_);                 \
      CC = skb[(size_t)kl_ * TLEN]; }                                          \
  }

#define SEG_BODY(MASKED, CLAMPED)                                              \
    PH(0,  c0, P, Q, nq0.x, MASKED, CLAMPED) PH(1,  c1, Q, P, nq0.y, MASKED, CLAMPED) \
    PH(2,  c2, P, Q, nq0.z, MASKED, CLAMPED) PH(3,  c3, Q, P, nq0.w, MASKED, CLAMPED) \
    PH(4,  c4, P, Q, nq1.x, MASKED, CLAMPED) PH(5,  c5, Q, P, nq1.y, MASKED, CLAMPED) \
    PH(6,  c6, P, Q, nq1.z, MASKED, CLAMPED) PH(7,  c7, Q, P, nq1.w, MASKED, CLAMPED) \
    PH(8,  c0, P, Q, nq2.x, MASKED, CLAMPED) PH(9,  c1, Q, P, nq2.y, MASKED, CLAMPED) \
    PH(10, c2, P, Q, nq2.z, MASKED, CLAMPED) PH(11, c3, Q, P, nq2.w, MASKED, CLAMPED) \
    PH(12, c4, P, Q, nq3.x, MASKED, CLAMPED) PH(13, c5, Q, P, nq3.y, MASKED, CLAMPED) \
    PH(14, c6, P, Q, nq3.z, MASKED, CLAMPED) PH(15, c7, Q, P, nq3.w, MASKED, CLAMPED)

#define PRIME(K)                                                               \
    c0 = skb[(size_t)clampi((K) + 0) * TLEN];                                  \
    c1 = skb[(size_t)clampi((K) + 1) * TLEN];                                  \
    c2 = skb[(size_t)clampi((K) + 2) * TLEN];                                  \
    c3 = skb[(size_t)clampi((K) + 3) * TLEN];                                  \
    c4 = skb[(size_t)clampi((K) + 4) * TLEN];                                  \
    c5 = skb[(size_t)clampi((K) + 5) * TLEN];                                  \
    c6 = skb[(size_t)clampi((K) + 6) * TLEN];                                  \
    c7 = skb[(size_t)clampi((K) + 7) * TLEN];

__global__ __launch_bounds__(512) void sdtw_dp(const half_t* __restrict__ skew,
                                               float* __restrict__ out) {
    const int b   = blockIdx.x;
    const int tid = threadIdx.x;
    const int ww  = tid >> 6;
    const int c   = ((ww & 3) << 1) | (ww >> 2);
    const int lt  = tid & 63;
    const int row = 64 * c + lt;
    const half_t* skb = skew + (size_t)b * (NDIAG * TLEN) + row;

    __shared__ float4 bnd4[9][8];
    if (tid < 288) ((float*)bnd4)[tid] = BIGV;

    float P = BIGV, Q = BIGV;
    float vBig  = BIGV;
    float bd_up = BIGV;
    float dgs   = (tid == 0) ? 0.0f : BIGV;
    float4 bq = make_float4(BIGV, BIGV, BIGV, BIGV);

    __syncthreads();

    half_t c0, c1, c2, c3, c4, c5, c6, c7;
    PRIME(-16 * c)

    for (int s = 0; s < 71; ++s) {
        const int sw  = s - 5 * c;
        const int kd0 = 16 * (s - c);
        const int q0  = (kd0 >> 2) & 7;
        const int vb0 = kd0 - row;

        if (sw >= -1 && sw <= 35) {
            float4 nq0 = bnd4[c][q0];
            float4 nq1 = bnd4[c][(q0 + 1) & 7];
            float4 nq2 = bnd4[c][(q0 + 2) & 7];
            float4 nq3 = bnd4[c][(q0 + 3) & 7];
            if (sw == -1) { PRIME(kd0) }
            if (sw >= 4 && sw <= 31) { SEG_BODY(0, 0) }
            else                     { SEG_BODY(1, 1) }
        } else {
            if (lt == 63) {
                float4 bigq = make_float4(BIGV, BIGV, BIGV, BIGV);
                bnd4[c + 1][q0]           = bigq;
                bnd4[c + 1][(q0 + 1) & 7] = bigq;
                bnd4[c + 1][(q0 + 2) & 7] = bigq;
                bnd4[c + 1][(q0 + 3) & 7] = bigq;
            }
        }
        __syncthreads();
    }

    if (tid == 511) out[b] = Q * LN2;
}

// ---------------------------------------------------------------- launcher
extern "C" void kernel_launch(void* const* d_in, const int* in_sizes, int n_in,
                              void* d_out, int out_size, void* d_ws, size_t ws_size,
                              hipStream_t stream) {
    const float* x = (const float*)d_in[0];
    const float* y = (const float*)d_in[1];
    float* outp = (float*)d_out;

    half_t*   skew = (half_t*)d_ws;                       // 16,760,832 halves
    unsigned* xnb  = (unsigned*)((char*)d_ws + (size_t)16760832 * 2);
    unsigned* ynb  = xnb + 1048576;

    sdtw_normcast<<<dim3(BT * TLEN / 4, 2), dim3(256), 0, stream>>>(x, y, xnb, ynb);
    sdtw_gemm_skew<<<dim3(4, 4, BT), dim3(256), 0, stream>>>(xnb, ynb, skew);
    sdtw_dp<<<dim3(BT), dim3(512), 0, stream>>>(skew, outp);
}

// Round 23
// 122.998 us; speedup vs baseline: 2.5748x; 1.0419x over previous
//
#include <hip/hip_runtime.h>
#include <hip/hip_bf16.h>
#include <cstdint>

// Problem: B=32, T1=T2=512, D=128, gamma=1.0
// out[b] = softDTW( 1 - cos_sim(x[b], y[b]) )
//
// R23 = R18 verbatim (measured best: 122.6 us).
//   normcast (~3 us) -> bf16 MFMA GEMM -> skew (~19 us) -> DP (~91 us).
// DP: 8 waves, stagger-16 segments, DPP lane-0 patch, hoisted boundary
// quads, JUNK/PARTIAL/INTERIOR segment modes — plateau after 10 falsified
// structural levers (R8-R22).
//
// ws layout:
//   skew : 32*1023*512 floats = 16,760,832
//   xnb  : 32*512*128 bf16 (1,048,576 uints)
//   ynb  : same

#define BT      32
#define TLEN    512
#define DF      128
#define NDIAG   1023          // kd = 0..1022
#define BIGV    1e30f
#define INV_LN2 1.44269504088896340f
#define LN2     0.69314718055994531f

typedef short bf16x8 __attribute__((ext_vector_type(8)));
typedef float f32x4  __attribute__((ext_vector_type(4)));

__device__ __forceinline__ unsigned f2bf(float f) {     // RNE f32 -> bf16 bits
    unsigned u = __builtin_bit_cast(unsigned, f);
    return (u + 0x7FFFu + ((u >> 16) & 1u)) >> 16;
}

// ---------------------------------------------- normalize + cast to bf16
// gridDim.y: 0 -> x, 1 -> y. One wave per row.
__global__ __launch_bounds__(256) void sdtw_normcast(const float* __restrict__ x,
                                                     const float* __restrict__ y,
                                                     unsigned* __restrict__ ox,
                                                     unsigned* __restrict__ oy) {
    const float* in  = blockIdx.y ? y : x;
    unsigned*    out = blockIdx.y ? oy : ox;
    int row = blockIdx.x * 4 + (threadIdx.x >> 6);
    int t   = threadIdx.x & 63;
    float2 v = reinterpret_cast<const float2*>(in + (size_t)row * DF)[t];
    float s = v.x * v.x + v.y * v.y;
    #pragma unroll
    for (int o = 32; o; o >>= 1) s += __shfl_xor(s, o);
    float scale = 1.0f / fmaxf(sqrtf(s), 1e-12f);
    out[(size_t)row * 64 + t] = f2bf(v.x * scale) | (f2bf(v.y * scale) << 16);
}

// ---------------------------------------------- bf16 MFMA GEMM -> skew
// 128x128 tile, 256 thr (4 waves), K=128 staged once: A_lds/B_lds [128][136]
// bf16 (16B row pad -> conflict-free ds_read_b128 fragments). Wave w owns
// cols [32w,32w+32): acc[8 rt][2 ct] f32x4, 64 MFMAs. Inputs pre-normalized
// -> cost = (1 - dot)/ln2 directly. Epilogue reuses LDS as cs[128][130] and
// scatters anti-diagonals (stride-129 reads conflict-free).
#define LDSTRIDE 272                         // bytes per LDS row (136 bf16)

__global__ __launch_bounds__(256) void sdtw_gemm_skew(const unsigned* __restrict__ xnb,
                                                      const unsigned* __restrict__ ynb,
                                                      float* __restrict__ skew) {
    __shared__ short smem[34816];            // 69,632 B: A 34,816 + B 34,816
    char* As = (char*)smem;
    char* Bs = (char*)smem + 34816;

    const int b  = blockIdx.z;
    const int r0 = blockIdx.y * 128;
    const int c0 = blockIdx.x * 128;
    const int tid = threadIdx.x;
    const int wid = tid >> 6, l = tid & 63;
    const int lr = l & 15, lg = l >> 4;

    const char* xg = (const char*)(xnb + ((size_t)b * TLEN + r0) * 64);
    const char* yg = (const char*)(ynb + ((size_t)b * TLEN + c0) * 64);

    #pragma unroll
    for (int p = 0; p < 8; ++p) {
        int idx = p * 256 + tid;
        int row = idx >> 4, u = idx & 15;
        *(uint4*)(As + row * LDSTRIDE + u * 16) = *(const uint4*)(xg + row * 256 + u * 16);
        *(uint4*)(Bs + row * LDSTRIDE + u * 16) = *(const uint4*)(yg + row * 256 + u * 16);
    }
    __syncthreads();

    f32x4 acc[8][2];
    #pragma unroll
    for (int rt = 0; rt < 8; ++rt)
        #pragma unroll
        for (int ct = 0; ct < 2; ++ct) acc[rt][ct] = (f32x4){0.f, 0.f, 0.f, 0.f};

    #pragma unroll
    for (int kb = 0; kb < 4; ++kb) {         // K chunks of 32
        bf16x8 af[8], bfr[2];
        #pragma unroll
        for (int rt = 0; rt < 8; ++rt)
            af[rt] = *(const bf16x8*)(As + (rt * 16 + lr) * LDSTRIDE + kb * 64 + lg * 16);
        #pragma unroll
        for (int ct = 0; ct < 2; ++ct)
            bfr[ct] = *(const bf16x8*)(Bs + (wid * 32 + ct * 16 + lr) * LDSTRIDE + kb * 64 + lg * 16);
        #pragma unroll
        for (int rt = 0; rt < 8; ++rt)
            #pragma unroll
            for (int ct = 0; ct < 2; ++ct)
                acc[rt][ct] = __builtin_amdgcn_mfma_f32_16x16x32_bf16(af[rt], bfr[ct], acc[rt][ct], 0, 0, 0);
    }

    __syncthreads();                         // all frag reads done; reuse LDS
    float* cs = (float*)smem;                // [128][130]
    #pragma unroll
    for (int rt = 0; rt < 8; ++rt)
        #pragma unroll
        for (int ct = 0; ct < 2; ++ct)
            #pragma unroll
            for (int r = 0; r < 4; ++r) {
                int row = rt * 16 + lg * 4 + r;          // C/D: row=(l>>4)*4+reg
                int col = wid * 32 + ct * 16 + lr;       //      col=l&15
                cs[row * 130 + col] = (1.0f - acc[rt][ct][r]) * INV_LN2;
            }
    __syncthreads();

    // anti-diagonal scatter: skew[kd*512 + r], contiguous in r
    float* sk = skew + (size_t)b * (NDIAG * TLEN);
    for (int dd = wid; dd < 255; dd += 4) {
        int lo = max(0, dd - 127), hi = min(127, dd);
        for (int rb = lo; rb <= hi; rb += 64) {
            int rl = rb + l;
            if (rl <= hi)
                sk[(size_t)(r0 + c0 + dd) * TLEN + r0 + rl] = cs[rl * 129 + dd]; // rl*130+(dd-rl)
        }
    }
}

// ----------------------------------------------------------------- DTW DP
// (R9/R14/R18 kernel, measured best ~91 us.)
__device__ __forceinline__ int clampi(int v) {
    return v < 0 ? 0 : (v > NDIAG - 1 ? NDIAG - 1 : v);
}

__device__ __forceinline__ float dpp_shr1_old(float old, float x) {
    return __builtin_bit_cast(float,
        __builtin_amdgcn_update_dpp(__builtin_bit_cast(int, old),
                                    __builtin_bit_cast(int, x),
                                    0x138 /*wave_shr:1*/, 0xF, 0xF, false));
}

#define PH(s, CC, PN, PO, NQC, MASKED, CLAMPED)                                \
  {                                                                            \
    float up_ = dpp_shr1_old(bd_up, PN);     /* lane0 <- bd_up */              \
    float dg_ = dgs;                         /* patched up_ of prev phase */   \
    float m_   = fminf(fminf(dg_, PN), up_);                                   \
    float mid_ = __builtin_amdgcn_fmed3f(dg_, PN, up_);                        \
    float mx_  = fmaxf(fmaxf(dg_, PN), up_);                                   \
    float e_   = 1.0f + __builtin_amdgcn_exp2f(m_ - mid_)                      \
                      + __builtin_amdgcn_exp2f(m_ - mx_);                      \
    float v_   = CC + m_ - __builtin_amdgcn_logf(e_);                          \
    PO = (MASKED) ? (((unsigned)(vb0 + (s)) < 512u) ? v_ : vBig) : v_;         \
    if (((s) & 3) == 0) bq.x = PO;                                             \
    if (((s) & 3) == 1) bq.y = PO;                                             \
    if (((s) & 3) == 2) bq.z = PO;                                             \
    if (((s) & 3) == 3) { bq.w = PO;                                           \
      if (lt == 63) bnd4[c + 1][(q0 + ((s) >> 2)) & 7] = bq; }                 \
    bd_up = (NQC);                                                             \
    dgs = up_;                                                                 \
    { int kl_ = kd0 + (s) + 8; if (CLAMPED) kl_ = clampi(kl_);                 \
      CC = skb[(size_t)kl_ * TLEN]; }                                          \
  }

#define SEG_BODY(MASKED, CLAMPED)                                              \
    PH(0,  c0, P, Q, nq0.x, MASKED, CLAMPED) PH(1,  c1, Q, P, nq0.y, MASKED, CLAMPED) \
    PH(2,  c2, P, Q, nq0.z, MASKED, CLAMPED) PH(3,  c3, Q, P, nq0.w, MASKED, CLAMPED) \
    PH(4,  c4, P, Q, nq1.x, MASKED, CLAMPED) PH(5,  c5, Q, P, nq1.y, MASKED, CLAMPED) \
    PH(6,  c6, P, Q, nq1.z, MASKED, CLAMPED) PH(7,  c7, Q, P, nq1.w, MASKED, CLAMPED) \
    PH(8,  c0, P, Q, nq2.x, MASKED, CLAMPED) PH(9,  c1, Q, P, nq2.y, MASKED, CLAMPED) \
    PH(10, c2, P, Q, nq2.z, MASKED, CLAMPED) PH(11, c3, Q, P, nq2.w, MASKED, CLAMPED) \
    PH(12, c4, P, Q, nq3.x, MASKED, CLAMPED) PH(13, c5, Q, P, nq3.y, MASKED, CLAMPED) \
    PH(14, c6, P, Q, nq3.z, MASKED, CLAMPED) PH(15, c7, Q, P, nq3.w, MASKED, CLAMPED)

#define PRIME(K)                                                               \
    c0 = skb[(size_t)clampi((K) + 0) * TLEN];                                  \
    c1 = skb[(size_t)clampi((K) + 1) * TLEN];                                  \
    c2 = skb[(size_t)clampi((K) + 2) * TLEN];                                  \
    c3 = skb[(size_t)clampi((K) + 3) * TLEN];                                  \
    c4 = skb[(size_t)clampi((K) + 4) * TLEN];                                  \
    c5 = skb[(size_t)clampi((K) + 5) * TLEN];                                  \
    c6 = skb[(size_t)clampi((K) + 6) * TLEN];                                  \
    c7 = skb[(size_t)clampi((K) + 7) * TLEN];

__global__ __launch_bounds__(512) void sdtw_dp(const float* __restrict__ skew,
                                               float* __restrict__ out) {
    const int b   = blockIdx.x;
    const int tid = threadIdx.x;
    const int ww  = tid >> 6;                    // hardware wave id
    const int c   = ((ww & 3) << 1) | (ww >> 2); // chunk (SIMD-aware remap)
    const int lt  = tid & 63;
    const int row = 64 * c + lt;
    const float* skb = skew + (size_t)b * (NDIAG * TLEN) + row;

    __shared__ float4 bnd4[9][8];                // [consumer chunk][quad slot]
    if (tid < 288) ((float*)bnd4)[tid] = BIGV;

    float P = BIGV, Q = BIGV;
    float vBig  = BIGV;
    float bd_up = BIGV;
    float dgs   = (tid == 0) ? 0.0f : BIGV;      // R(0,0)=0 at kd=0 (chunk0 lane0)
    float4 bq = make_float4(BIGV, BIGV, BIGV, BIGV);

    __syncthreads();

    float c0, c1, c2, c3, c4, c5, c6, c7;
    PRIME(-16 * c)                               // real for chunk 0; re-primed at warm-up

    for (int s = 0; s < 71; ++s) {
        const int sw  = s - 5 * c;               // wave-uniform
        const int kd0 = 16 * (s - c);
        const int q0  = (kd0 >> 2) & 7;
        const int vb0 = kd0 - row;

        if (sw >= -1 && sw <= 35) {
            float4 nq0 = bnd4[c][q0];
            float4 nq1 = bnd4[c][(q0 + 1) & 7];
            float4 nq2 = bnd4[c][(q0 + 2) & 7];
            float4 nq3 = bnd4[c][(q0 + 3) & 7];
            if (sw == -1) { PRIME(kd0) }         // warm-up: re-prime prefetch
            if (sw >= 4 && sw <= 31) { SEG_BODY(0, 0) }   // interior
            else                     { SEG_BODY(1, 1) }   // staircase/warm-up
        } else {
            if (lt == 63) {                      // junk: keep boundary cadence
                float4 bigq = make_float4(BIGV, BIGV, BIGV, BIGV);
                bnd4[c + 1][q0]           = bigq;
                bnd4[c + 1][(q0 + 1) & 7] = bigq;
                bnd4[c + 1][(q0 + 2) & 7] = bigq;
                bnd4[c + 1][(q0 + 3) & 7] = bigq;
            }
        }
        __syncthreads();
    }

    if (tid == 511) out[b] = Q * LN2;            // chunk 7, row 511: R'(512,512)*ln2
}

// ---------------------------------------------------------------- launcher
extern "C" void kernel_launch(void* const* d_in, const int* in_sizes, int n_in,
                              void* d_out, int out_size, void* d_ws, size_t ws_size,
                              hipStream_t stream) {
    const float* x = (const float*)d_in[0];
    const float* y = (const float*)d_in[1];
    float* outp = (float*)d_out;

    float*    skew = (float*)d_ws;                        // 16,760,832 floats
    unsigned* xnb  = (unsigned*)(skew + (size_t)16760832);
    unsigned* ynb  = xnb + 1048576;

    sdtw_normcast<<<dim3(BT * TLEN / 4, 2), dim3(256), 0, stream>>>(x, y, xnb, ynb);
    sdtw_gemm_skew<<<dim3(4, 4, BT), dim3(256), 0, stream>>>(xnb, ynb, skew);
    sdtw_dp<<<dim3(BT), dim3(512), 0, stream>>>(skew, outp);
}